// Round 10
// baseline (20.090 us; speedup 1.0000x reference)
//
#include <hip/hip_runtime.h>
#include <math.h>

#define IMG   112
#define HW    12544
#define GRID  16
#define DP    384
#define CF    128
#define CIN   512
#define COUT  128
#define KTOP  64
#define NHEADS 6
#define NBIN  8192   // 13-bit bins of the orderable key
#define CAP   2048   // candidate capacity (expected ~100 for Gaussian data)
#define NYP   14     // rows per thread: 8 y-blocks x 14 = 112

// Replicate jax f32 sample position: fl32((i+0.5f)*fl32(16/112)) - 0.5f.
// Double product + truncation = exact f32 round-to-nearest multiply, not fusable.
__device__ __forceinline__ float sample_pos(int i) {
    const double inv = (double)(16.0f / 112.0f);
    float prod = (float)(((double)i + 0.5) * inv);
    return prod - 0.5f;
}

struct BL { int i0, i1; float w; };

__device__ __forceinline__ BL bl_coeff(int i) {
    float s = sample_pos(i);
    s = fminf(fmaxf(s, 0.0f), 15.0f);   // clamp FIRST -> clamp groups bit-identical
    int i0 = (int)s;
    if (i0 > GRID - 2) i0 = GRID - 2;
    BL r;
    r.i0 = i0;
    r.i1 = i0 + 1;
    r.w  = s - (float)i0;               // exact (Sterbenz)
    return r;
}

// Orderable transform: ascending finite float <-> ascending unsigned.
__device__ __forceinline__ unsigned ordkey(float f) {
    unsigned u = __float_as_uint(f);
    return u ^ ((u & 0x80000000u) ? 0xFFFFFFFFu : 0x80000000u);
}

// Fused: each block (g, b) redundantly computes batch b's top-64 (phase 1),
// then computes features for its own 4 pixels (phase 2).
// Phase 1 uses the separability of bilinear resize: rp[yi][x] holds the
// reference's (top, bot) row-interpolations verbatim, so the per-pixel value
// v = (1-wy)*rp.x + wy*rp.y is bit-identical to the verified kernels.
// Main loop is column-major: thread owns column xl, iterates 14 consecutive
// rows -> tc[y] reads are wave-uniform broadcasts, rp[] is register-cached
// (wave-uniform re-read when yi0 steps), only the histogram atomic is
// per-pixel. 896 active threads x 14 rows = 12544 exactly (no tail).
// Histogram: 13-bit bins, two 16-bit counters per u32 word
// (max count per copy = 256 threads * 14 px = 3584 << 65536, no carry).
extern "C" __global__ void __launch_bounds__(1024)
fused_kernel(const float* __restrict__ attn, const float* __restrict__ lf,
             const float* __restrict__ pt, const float* __restrict__ cw,
             const float* __restrict__ cb, const float* __restrict__ bg,
             const float* __restrict__ bb, const float* __restrict__ bm,
             const float* __restrict__ bvr, float* __restrict__ out) {
    __shared__ __align__(16) float    amean[GRID * GRID];
    __shared__ __align__(16) float2   tc[IMG];
    __shared__ __align__(16) float2   rp[15 * 128];      // [yi][x], x padded to 128
    __shared__ __align__(16) unsigned hist[4][NBIN / 2]; // 64 KB, 4 copies, packed
    __shared__ unsigned wtot[16];
    __shared__ unsigned s_T;
    __shared__ int      s_nc;
    __shared__ __align__(16) unsigned long long candp[CAP];
    __shared__ int      topidx[KTOP];
    __shared__ __align__(16) float comb[4][CIN];   // 8 KB
    __shared__ __align__(16) float vmat[4][COUT];
    __shared__ float snrm[4];

    const int g = blockIdx.x;    // pixel group: 4 topk pixels
    const int b = blockIdx.y;    // batch
    const int t = threadIdx.x;
    const int lane = t & 63;
    const int wv = t >> 6;       // 0..15
    const int hc = wv >> 2;      // 4 histogram copies

    // ---------------- phase 1: top-64 for batch b ----------------
    if (t < 256) {
        float s = 0.0f;
        for (int h = 0; h < NHEADS; ++h)
            s += attn[(((size_t)b * NHEADS + h) << 8) + t];
        amean[t] = s * (1.0f / 6.0f);
    } else if (t < 256 + IMG) {
        int i = t - 256;
        BL c = bl_coeff(i);
        tc[i] = make_float2(__int_as_float(c.i0), c.w);
    }
    // zero 4 packed histogram copies with b128 writes (4 per thread)
    {
        uint4* h4 = (uint4*)hist;
        const uint4 z = make_uint4(0, 0, 0, 0);
#pragma unroll
        for (int i = 0; i < 4; ++i) h4[t + i * 1024] = z;
    }
    if (t == 0) s_nc = 0;
    __syncthreads();

    // build rp[yi][x] = {top, bot} row-interpolations (reference expressions)
    for (int e = t; e < 15 * 128; e += 1024) {
        const int yi = e >> 7, x = e & 127;
        if (x < IMG) {
            float2 tx = tc[x];
            const int xi0 = __float_as_int(tx.x);
            const float wx = tx.y;
            const float* r0 = &amean[yi * GRID];
            float top = (1.0f - wx) * r0[xi0] + wx * r0[xi0 + 1];
            float bot = (1.0f - wx) * r0[GRID + xi0] + wx * r0[GRID + xi0 + 1];
            rp[e] = make_float2(top, bot);
        }
    }
    __syncthreads();

    // column-major sweep: xl fixed per thread (odd-multiplier scramble keeps
    // lanes' histogram bins decorrelated), y runs over 14 consecutive rows.
    const int xl = (t * 85) & 127;       // bijection on 0..127
    const int yb = t >> 7;               // 0..7
    const bool act = xl < IMG;
    unsigned lk[NYP];
    {
        int   yic = -1;
        float2 pr = make_float2(0.0f, 0.0f);
#pragma unroll
        for (int j = 0; j < NYP; ++j) {
            const int y = yb * NYP + j;
            float2 ty = tc[y];                    // wave-uniform broadcast
            const int yi0 = __float_as_int(ty.x);
            if (yi0 != yic) {                     // wave-uniform branch
                if (act) pr = rp[yi0 * 128 + xl];
                yic = yi0;
            }
            float v = (1.0f - ty.y) * pr.x + ty.y * pr.y;
            unsigned key = ordkey(v);
            lk[j] = key;
            if (act) {
                const unsigned bin = key >> 19;
                atomicAdd(&hist[hc][bin >> 1], 1u << ((bin & 1) << 4));
            }
        }
    }
    __syncthreads();

    // block-wide suffix scan over 8192 bins (8 bins = 4 words per thread):
    // find bin T with count(bin >= T) >= 64 > count(bin >= T+1)
    unsigned cnt[8] = {0, 0, 0, 0, 0, 0, 0, 0};
#pragma unroll
    for (int k = 0; k < 4; ++k) {
        uint4 h4 = ((const uint4*)&hist[k][0])[t];   // words 4t..4t+3
        cnt[0] += h4.x & 0xFFFFu; cnt[1] += h4.x >> 16;
        cnt[2] += h4.y & 0xFFFFu; cnt[3] += h4.y >> 16;
        cnt[4] += h4.z & 0xFFFFu; cnt[5] += h4.z >> 16;
        cnt[6] += h4.w & 0xFFFFu; cnt[7] += h4.w >> 16;
    }
    unsigned tot = 0;
#pragma unroll
    for (int i = 0; i < 8; ++i) tot += cnt[i];
    unsigned v = tot;   // inclusive suffix within wave
    for (int off = 1; off < 64; off <<= 1) {
        unsigned o = __shfl_down(v, off);
        if (lane + off < 64) v += o;
    }
    if (lane == 0) wtot[wv] = v;
    __syncthreads();
    unsigned add = 0;
    for (int w = wv + 1; w < 16; ++w) add += wtot[w];
    const unsigned S = v + add;          // count in bins >= t*8
    unsigned suf = S - tot;              // count in bins >= (t+1)*8
#pragma unroll
    for (int i = 7; i >= 0; --i) {       // exactly one (t,i) brackets KTOP
        unsigned cum = suf + cnt[i];
        if (cum >= KTOP && suf < KTOP) s_T = (unsigned)(t * 8 + i);
        suf = cum;
    }
    __syncthreads();
    const unsigned T = s_T;

    // collect candidates with bin >= T, packed (key desc, idx asc) == desc u64:
    // P = (key << 14) | (16383 - idx)
    if (act) {
#pragma unroll
        for (int j = 0; j < NYP; ++j) {
            unsigned key = lk[j];
            if ((key >> 19) >= T) {
                int sl = atomicAdd(&s_nc, 1);
                if (sl < CAP)
                    candp[sl] = ((unsigned long long)key << 14)
                              | (unsigned)(16383 - ((yb * NYP + j) * IMG + xl));
            }
        }
    }
    __syncthreads();

    // exact stable rank select, 4 threads per candidate (rank depends only on
    // the candidate SET): rank = #{P2 > P}; order == jax.lax.top_k
    const int n = s_nc < CAP ? s_nc : CAP;
    const int q = t & 3;
    for (int c = t >> 2; c < n; c += 256) {
        const unsigned long long myp = candp[c];
        int r = 0;
        for (int j2 = q; j2 < n; j2 += 4)
            r += (candp[j2] > myp);
        r += __shfl_xor(r, 1);
        r += __shfl_xor(r, 2);
        if (q == 0 && r < KTOP)
            topidx[r] = 16383 - (int)(myp & 16383u);
    }
    __syncthreads();

    // ---------------- phase 2: features for this block's 4 pixels ----------------
    int pidx[4];
#pragma unroll
    for (int i = 0; i < 4; ++i) pidx[i] = topidx[g * 4 + i];

    int   yi0a[4], xi0a[4];
    float wyv[4], wxv[4];
#pragma unroll
    for (int px = 0; px < 4; ++px) {
        const int idx = pidx[px];
        const int y = idx / IMG, x = idx - y * IMG;
        BL by = bl_coeff(y), bx = bl_coeff(x);
        yi0a[px] = by.i0; xi0a[px] = bx.i0; wyv[px] = by.w; wxv[px] = bx.w;
    }
    // stage comb[4][512]: thread -> (c = t&511, px = (t>>9)*2 + pp)
    {
        const int c = t & 511;
        const int ph = t >> 9;
        const float* ptb = pt + (size_t)b * 256 * DP;
#pragma unroll
        for (int pp = 0; pp < 2; ++pp) {
            const int px = ph * 2 + pp;
            float val;
            if (c < DP) {
                const int base = yi0a[px] * GRID + xi0a[px];
                float p00 = ptb[(size_t)base * DP + c];
                float p01 = ptb[(size_t)(base + 1) * DP + c];
                float p10 = ptb[(size_t)(base + GRID) * DP + c];
                float p11 = ptb[(size_t)(base + GRID + 1) * DP + c];
                float top = (1.0f - wxv[px]) * p00 + wxv[px] * p01;
                float bot = (1.0f - wxv[px]) * p10 + wxv[px] * p11;
                val = (1.0f - wyv[px]) * top + wyv[px] * bot;
            } else {
                val = lf[((size_t)b * CF + (c - DP)) * HW + pidx[px]];
            }
            comb[px][c] = val;
        }
    }
    __syncthreads();

    // Register-tiled GEMV (threads 0..511): thread (c4 = t>>4, l = t&15)
    // owns a 4px x 4ch accumulator tile over K-slice {i*64 + l*4}.
    if (t < 512) {
        const int c4 = t >> 4, l = t & 15;
        float acc[4][4];   // [px][j]
#pragma unroll
        for (int p = 0; p < 4; ++p)
#pragma unroll
            for (int j = 0; j < 4; ++j) acc[p][j] = 0.0f;

        const float* wbase = cw + (size_t)c4 * 4 * CIN + l * 4;
#pragma unroll
        for (int i = 0; i < 8; ++i) {
            const int k = i * 64 + l * 4;
            float4 w0 = *(const float4*)(wbase + i * 64);
            float4 w1 = *(const float4*)(wbase + CIN + i * 64);
            float4 w2 = *(const float4*)(wbase + 2 * CIN + i * 64);
            float4 w3 = *(const float4*)(wbase + 3 * CIN + i * 64);
            float4 q0 = *(const float4*)(&comb[0][k]);
            float4 q1 = *(const float4*)(&comb[1][k]);
            float4 q2 = *(const float4*)(&comb[2][k]);
            float4 q3 = *(const float4*)(&comb[3][k]);
#define DOT4(W, C) ((W).x * (C).x + (W).y * (C).y + (W).z * (C).z + (W).w * (C).w)
            acc[0][0] += DOT4(w0, q0); acc[0][1] += DOT4(w1, q0);
            acc[0][2] += DOT4(w2, q0); acc[0][3] += DOT4(w3, q0);
            acc[1][0] += DOT4(w0, q1); acc[1][1] += DOT4(w1, q1);
            acc[1][2] += DOT4(w2, q1); acc[1][3] += DOT4(w3, q1);
            acc[2][0] += DOT4(w0, q2); acc[2][1] += DOT4(w1, q2);
            acc[2][2] += DOT4(w2, q2); acc[2][3] += DOT4(w3, q2);
            acc[3][0] += DOT4(w0, q3); acc[3][1] += DOT4(w1, q3);
            acc[3][2] += DOT4(w2, q3); acc[3][3] += DOT4(w3, q3);
#undef DOT4
        }
        // reduce K-split across the 16-lane group (in-wave shuffles)
#pragma unroll
        for (int p = 0; p < 4; ++p)
#pragma unroll
            for (int j = 0; j < 4; ++j) {
                acc[p][j] += __shfl_xor(acc[p][j], 1);
                acc[p][j] += __shfl_xor(acc[p][j], 2);
                acc[p][j] += __shfl_xor(acc[p][j], 4);
                acc[p][j] += __shfl_xor(acc[p][j], 8);
            }
        if (l == 0) {
#pragma unroll
            for (int j = 0; j < 4; ++j) {
                const int ch = c4 * 4 + j;
                float scale = bg[ch] / sqrtf(bvr[ch] + 1e-5f);
                float shift = bb[ch] - bm[ch] * scale;
                float base  = cb[ch];
#pragma unroll
                for (int p = 0; p < 4; ++p)
                    vmat[p][ch] = fmaxf((base + acc[p][j]) * scale + shift, 0.0f);
            }
        }
    }
    __syncthreads();

    // L2 norm per pixel (waves 0-3, one pixel each)
    if (wv < 4) {
        float x0 = vmat[wv][lane], x1 = vmat[wv][lane + 64];
        float ss = x0 * x0 + x1 * x1;
        for (int off = 32; off > 0; off >>= 1) ss += __shfl_xor(ss, off);
        if (lane == 0) snrm[wv] = sqrtf(ss);
    }
    __syncthreads();

    if (t < 512) {
        const int px = t & 3, c2 = t >> 2;
        out[((size_t)(b * COUT + c2)) * KTOP + g * 4 + px] =
            vmat[px][c2] / fmaxf(snrm[px], 1e-12f);
    }
}

extern "C" void kernel_launch(void* const* d_in, const int* in_sizes, int n_in,
                              void* d_out, int out_size, void* d_ws, size_t ws_size,
                              hipStream_t stream) {
    const float* lf   = (const float*)d_in[0];
    const float* pt   = (const float*)d_in[1];
    const float* attn = (const float*)d_in[2];
    const float* cw   = (const float*)d_in[3];
    const float* cb   = (const float*)d_in[4];
    const float* bg   = (const float*)d_in[5];
    const float* bb   = (const float*)d_in[6];
    const float* bm   = (const float*)d_in[7];
    const float* bvr  = (const float*)d_in[8];
    float* out = (float*)d_out;
    const int B = in_sizes[0] / (CF * HW);

    hipLaunchKernelGGL(fused_kernel, dim3(KTOP / 4, B), dim3(1024), 0, stream,
                       attn, lf, pt, cw, cb, bg, bb, bm, bvr, out);
}

// Round 11
// 19.569 us; speedup vs baseline: 1.0266x; 1.0266x over previous
//
#include <hip/hip_runtime.h>
#include <math.h>

#define IMG   112
#define HW    12544
#define GRID  16
#define DP    384
#define CF    128
#define CIN   512
#define COUT  128
#define KTOP  64
#define NHEADS 6
#define NBIN  8192   // 13-bit bins of the orderable key
#define CAP   2048   // candidate capacity (expected ~100 for Gaussian data)
#define NJ    12     // 12*1024 + 256 = 12544

// Replicate jax f32 sample position: fl32((i+0.5f)*fl32(16/112)) - 0.5f.
// Double product + truncation = exact f32 round-to-nearest multiply, not fusable.
__device__ __forceinline__ float sample_pos(int i) {
    const double inv = (double)(16.0f / 112.0f);
    float prod = (float)(((double)i + 0.5) * inv);
    return prod - 0.5f;
}

struct BL { int i0, i1; float w; };

__device__ __forceinline__ BL bl_coeff(int i) {
    float s = sample_pos(i);
    s = fminf(fmaxf(s, 0.0f), 15.0f);   // clamp FIRST -> clamp groups bit-identical
    int i0 = (int)s;
    if (i0 > GRID - 2) i0 = GRID - 2;
    BL r;
    r.i0 = i0;
    r.i1 = i0 + 1;
    r.w  = s - (float)i0;               // exact (Sterbenz)
    return r;
}

// Orderable transform: ascending finite float <-> ascending unsigned.
__device__ __forceinline__ unsigned ordkey(float f) {
    unsigned u = __float_as_uint(f);
    return u ^ ((u & 0x80000000u) ? 0xFFFFFFFFu : 0x80000000u);
}

// Fused: each block (g, b) redundantly computes batch b's top-64 (phase 1),
// then computes features for its own 4 pixels (phase 2).
// Phase 1 uses the separability of bilinear resize: rp[yi][x] holds the
// reference's (top, bot) row-interpolations verbatim, so the per-pixel value
// v = (1-wy)*rp.x + wy*rp.y is bit-identical to the verified kernels.
// Histogram: 13-bit bins, two 16-bit counters packed per u32 word
// (max count per copy = 256 threads * 13 px = 3328 << 65536, no carry).
// GEMV weight stream overlap: the first 2 weight iterations are prefetched
// into registers right after candidate collection (weights depend on no LDS
// state), so the L2 stream starts under rank-select + staging.
extern "C" __global__ void __launch_bounds__(1024)
fused_kernel(const float* __restrict__ attn, const float* __restrict__ lf,
             const float* __restrict__ pt, const float* __restrict__ cw,
             const float* __restrict__ cb, const float* __restrict__ bg,
             const float* __restrict__ bb, const float* __restrict__ bm,
             const float* __restrict__ bvr, float* __restrict__ out) {
    __shared__ __align__(16) float    amean[GRID * GRID];
    __shared__ __align__(16) float2   tc[IMG];
    __shared__ __align__(16) float2   rp[15 * 128];      // [yi][x], x padded to 128
    __shared__ __align__(16) unsigned hist[4][NBIN / 2]; // 64 KB, 4 copies, packed
    __shared__ unsigned wtot[16];
    __shared__ unsigned s_T;
    __shared__ int      s_nc;
    __shared__ __align__(16) unsigned long long candp[CAP];
    __shared__ int      topidx[KTOP];
    __shared__ __align__(16) float comb[4][CIN];   // 8 KB
    __shared__ __align__(16) float vmat[4][COUT];
    __shared__ float snrm[4];

    const int g = blockIdx.x;    // pixel group: 4 topk pixels
    const int b = blockIdx.y;    // batch
    const int t = threadIdx.x;
    const int lane = t & 63;
    const int wv = t >> 6;       // 0..15
    const int hc = wv >> 2;      // 4 histogram copies

    // ---------------- phase 1: top-64 for batch b ----------------
    if (t < 256) {
        float s = 0.0f;
        for (int h = 0; h < NHEADS; ++h)
            s += attn[(((size_t)b * NHEADS + h) << 8) + t];
        amean[t] = s * (1.0f / 6.0f);
    } else if (t < 256 + IMG) {
        int i = t - 256;
        BL c = bl_coeff(i);
        tc[i] = make_float2(__int_as_float(c.i0), c.w);
    }
    // zero 4 packed histogram copies with b128 writes (4 per thread)
    {
        uint4* h4 = (uint4*)hist;
        const uint4 z = make_uint4(0, 0, 0, 0);
#pragma unroll
        for (int i = 0; i < 4; ++i) h4[t + i * 1024] = z;
    }
    if (t == 0) s_nc = 0;
    __syncthreads();

    // build rp[yi][x] = {top, bot} row-interpolations (reference expressions)
    for (int e = t; e < 15 * 128; e += 1024) {
        const int yi = e >> 7, x = e & 127;
        if (x < IMG) {
            float2 tx = tc[x];
            const int xi0 = __float_as_int(tx.x);
            const float wx = tx.y;
            const float* r0 = &amean[yi * GRID];
            float top = (1.0f - wx) * r0[xi0] + wx * r0[xi0 + 1];
            float bot = (1.0f - wx) * r0[GRID + xi0] + wx * r0[GRID + xi0 + 1];
            rp[e] = make_float2(top, bot);
        }
    }
    __syncthreads();

    // 12.25 resized values per thread. Lane->pixel stride 85 (odd) gives full
    // bank spread on rp reads and decorrelates histogram bins within a wave.
    // (y,x) advanced incrementally: step 1024 = 9*112 + 16 (no per-pixel div).
    const int pt_ = (t * 85) & 1023;   // bijection on 0..1023
    unsigned lk[NJ];
    unsigned tailk = 0;
    {
        int y = pt_ / IMG, x = pt_ - (pt_ / IMG) * IMG;
#pragma unroll
        for (int j = 0; j < NJ; ++j) {
            float2 ty = tc[y];
            const int yi0 = __float_as_int(ty.x);
            const float wy = ty.y;
            float2 pr = rp[yi0 * 128 + x];
            float v = (1.0f - wy) * pr.x + wy * pr.y;
            unsigned key = ordkey(v);
            lk[j] = key;
            const unsigned bin = key >> 19;
            atomicAdd(&hist[hc][bin >> 1], 1u << ((bin & 1) << 4));
            x += 16; y += 9;
            if (x >= IMG) { x -= IMG; y += 1; }
        }
    }
    if (t < 256) {
        const int idx = NJ * 1024 + t;
        const int y = idx / IMG, x = idx - y * IMG;
        float2 ty = tc[y];
        float2 pr = rp[__float_as_int(ty.x) * 128 + x];
        float v = (1.0f - ty.y) * pr.x + ty.y * pr.y;
        tailk = ordkey(v);
        const unsigned bin = tailk >> 19;
        atomicAdd(&hist[hc][bin >> 1], 1u << ((bin & 1) << 4));
    }
    __syncthreads();

    // block-wide suffix scan over 8192 bins (8 bins = 4 words per thread):
    // find bin T with count(bin >= T) >= 64 > count(bin >= T+1)
    unsigned cnt[8] = {0, 0, 0, 0, 0, 0, 0, 0};
#pragma unroll
    for (int k = 0; k < 4; ++k) {
        uint4 h4 = ((const uint4*)&hist[k][0])[t];   // words 4t..4t+3
        cnt[0] += h4.x & 0xFFFFu; cnt[1] += h4.x >> 16;
        cnt[2] += h4.y & 0xFFFFu; cnt[3] += h4.y >> 16;
        cnt[4] += h4.z & 0xFFFFu; cnt[5] += h4.z >> 16;
        cnt[6] += h4.w & 0xFFFFu; cnt[7] += h4.w >> 16;
    }
    unsigned tot = 0;
#pragma unroll
    for (int i = 0; i < 8; ++i) tot += cnt[i];
    unsigned v = tot;   // inclusive suffix within wave
    for (int off = 1; off < 64; off <<= 1) {
        unsigned o = __shfl_down(v, off);
        if (lane + off < 64) v += o;
    }
    if (lane == 0) wtot[wv] = v;
    __syncthreads();
    unsigned add = 0;
    for (int w = wv + 1; w < 16; ++w) add += wtot[w];
    const unsigned S = v + add;          // count in bins >= t*8
    unsigned suf = S - tot;              // count in bins >= (t+1)*8
#pragma unroll
    for (int i = 7; i >= 0; --i) {       // exactly one (t,i) brackets KTOP
        unsigned cum = suf + cnt[i];
        if (cum >= KTOP && suf < KTOP) s_T = (unsigned)(t * 8 + i);
        suf = cum;
    }
    __syncthreads();
    const unsigned T = s_T;

    // collect candidates with bin >= T, packed (key desc, idx asc) == desc u64:
    // P = (key << 14) | (16383 - idx)
#pragma unroll
    for (int j = 0; j < NJ; ++j) {
        unsigned key = lk[j];
        if ((key >> 19) >= T) {
            int sl = atomicAdd(&s_nc, 1);
            if (sl < CAP)
                candp[sl] = ((unsigned long long)key << 14)
                          | (unsigned)(16383 - (j * 1024 + pt_));
        }
    }
    if (t < 256 && (tailk >> 19) >= T) {
        int sl = atomicAdd(&s_nc, 1);
        if (sl < CAP)
            candp[sl] = ((unsigned long long)tailk << 14)
                      | (unsigned)(16383 - (NJ * 1024 + t));
    }
    __syncthreads();

    // prefetch the first 2 GEMV weight iterations into registers: independent
    // of all LDS state, issues the L2 weight stream under rank-select+staging.
    // (Loads cannot be sunk below __syncthreads by the compiler.)
    float4 wp[8];
    if (t < 512) {
        const int c4p = t >> 4, lp = t & 15;
        const float* wb = cw + (size_t)c4p * 4 * CIN + lp * 4;
#pragma unroll
        for (int i = 0; i < 2; ++i)
#pragma unroll
            for (int j = 0; j < 4; ++j)
                wp[i * 4 + j] = *(const float4*)(wb + (size_t)j * CIN + i * 64);
    }

    // exact stable rank select, 4 threads per candidate (rank depends only on
    // the candidate SET): rank = #{P2 > P}; order == jax.lax.top_k
    const int n = s_nc < CAP ? s_nc : CAP;
    const int q = t & 3;
    for (int c = t >> 2; c < n; c += 256) {
        const unsigned long long myp = candp[c];
        int r = 0;
        for (int j2 = q; j2 < n; j2 += 4)
            r += (candp[j2] > myp);
        r += __shfl_xor(r, 1);
        r += __shfl_xor(r, 2);
        if (q == 0 && r < KTOP)
            topidx[r] = 16383 - (int)(myp & 16383u);
    }
    __syncthreads();

    // ---------------- phase 2: features for this block's 4 pixels ----------------
    int pidx[4];
#pragma unroll
    for (int i = 0; i < 4; ++i) pidx[i] = topidx[g * 4 + i];

    int   yi0a[4], xi0a[4];
    float wyv[4], wxv[4];
#pragma unroll
    for (int px = 0; px < 4; ++px) {
        const int idx = pidx[px];
        const int y = idx / IMG, x = idx - y * IMG;
        BL by = bl_coeff(y), bx = bl_coeff(x);
        yi0a[px] = by.i0; xi0a[px] = bx.i0; wyv[px] = by.w; wxv[px] = bx.w;
    }
    // stage comb[4][512]: thread -> (c = t&511, px = (t>>9)*2 + pp)
    {
        const int c = t & 511;
        const int ph = t >> 9;
        const float* ptb = pt + (size_t)b * 256 * DP;
#pragma unroll
        for (int pp = 0; pp < 2; ++pp) {
            const int px = ph * 2 + pp;
            float val;
            if (c < DP) {
                const int base = yi0a[px] * GRID + xi0a[px];
                float p00 = ptb[(size_t)base * DP + c];
                float p01 = ptb[(size_t)(base + 1) * DP + c];
                float p10 = ptb[(size_t)(base + GRID) * DP + c];
                float p11 = ptb[(size_t)(base + GRID + 1) * DP + c];
                float top = (1.0f - wxv[px]) * p00 + wxv[px] * p01;
                float bot = (1.0f - wxv[px]) * p10 + wxv[px] * p11;
                val = (1.0f - wyv[px]) * top + wyv[px] * bot;
            } else {
                val = lf[((size_t)b * CF + (c - DP)) * HW + pidx[px]];
            }
            comb[px][c] = val;
        }
    }
    __syncthreads();

    // Register-tiled GEMV (threads 0..511): thread (c4 = t>>4, l = t&15)
    // owns a 4px x 4ch accumulator tile over K-slice {i*64 + l*4}.
    if (t < 512) {
        const int c4 = t >> 4, l = t & 15;
        float acc[4][4];   // [px][j]
#pragma unroll
        for (int p = 0; p < 4; ++p)
#pragma unroll
            for (int j = 0; j < 4; ++j) acc[p][j] = 0.0f;

        const float* wbase = cw + (size_t)c4 * 4 * CIN + l * 4;
#pragma unroll
        for (int i = 0; i < 8; ++i) {
            const int k = i * 64 + l * 4;
            float4 w0, w1, w2, w3;
            if (i < 2) {
                w0 = wp[i * 4 + 0]; w1 = wp[i * 4 + 1];
                w2 = wp[i * 4 + 2]; w3 = wp[i * 4 + 3];
            } else {
                w0 = *(const float4*)(wbase + i * 64);
                w1 = *(const float4*)(wbase + CIN + i * 64);
                w2 = *(const float4*)(wbase + 2 * CIN + i * 64);
                w3 = *(const float4*)(wbase + 3 * CIN + i * 64);
            }
            float4 q0 = *(const float4*)(&comb[0][k]);
            float4 q1 = *(const float4*)(&comb[1][k]);
            float4 q2 = *(const float4*)(&comb[2][k]);
            float4 q3 = *(const float4*)(&comb[3][k]);
#define DOT4(W, C) ((W).x * (C).x + (W).y * (C).y + (W).z * (C).z + (W).w * (C).w)
            acc[0][0] += DOT4(w0, q0); acc[0][1] += DOT4(w1, q0);
            acc[0][2] += DOT4(w2, q0); acc[0][3] += DOT4(w3, q0);
            acc[1][0] += DOT4(w0, q1); acc[1][1] += DOT4(w1, q1);
            acc[1][2] += DOT4(w2, q1); acc[1][3] += DOT4(w3, q1);
            acc[2][0] += DOT4(w0, q2); acc[2][1] += DOT4(w1, q2);
            acc[2][2] += DOT4(w2, q2); acc[2][3] += DOT4(w3, q2);
            acc[3][0] += DOT4(w0, q3); acc[3][1] += DOT4(w1, q3);
            acc[3][2] += DOT4(w2, q3); acc[3][3] += DOT4(w3, q3);
#undef DOT4
        }
        // reduce K-split across the 16-lane group (in-wave shuffles)
#pragma unroll
        for (int p = 0; p < 4; ++p)
#pragma unroll
            for (int j = 0; j < 4; ++j) {
                acc[p][j] += __shfl_xor(acc[p][j], 1);
                acc[p][j] += __shfl_xor(acc[p][j], 2);
                acc[p][j] += __shfl_xor(acc[p][j], 4);
                acc[p][j] += __shfl_xor(acc[p][j], 8);
            }
        if (l == 0) {
#pragma unroll
            for (int j = 0; j < 4; ++j) {
                const int ch = c4 * 4 + j;
                float scale = bg[ch] / sqrtf(bvr[ch] + 1e-5f);
                float shift = bb[ch] - bm[ch] * scale;
                float base  = cb[ch];
#pragma unroll
                for (int p = 0; p < 4; ++p)
                    vmat[p][ch] = fmaxf((base + acc[p][j]) * scale + shift, 0.0f);
            }
        }
    }
    __syncthreads();

    // L2 norm per pixel (waves 0-3, one pixel each)
    if (wv < 4) {
        float x0 = vmat[wv][lane], x1 = vmat[wv][lane + 64];
        float ss = x0 * x0 + x1 * x1;
        for (int off = 32; off > 0; off >>= 1) ss += __shfl_xor(ss, off);
        if (lane == 0) snrm[wv] = sqrtf(ss);
    }
    __syncthreads();

    if (t < 512) {
        const int px = t & 3, c2 = t >> 2;
        out[((size_t)(b * COUT + c2)) * KTOP + g * 4 + px] =
            vmat[px][c2] / fmaxf(snrm[px], 1e-12f);
    }
}

extern "C" void kernel_launch(void* const* d_in, const int* in_sizes, int n_in,
                              void* d_out, int out_size, void* d_ws, size_t ws_size,
                              hipStream_t stream) {
    const float* lf   = (const float*)d_in[0];
    const float* pt   = (const float*)d_in[1];
    const float* attn = (const float*)d_in[2];
    const float* cw   = (const float*)d_in[3];
    const float* cb   = (const float*)d_in[4];
    const float* bg   = (const float*)d_in[5];
    const float* bb   = (const float*)d_in[6];
    const float* bm   = (const float*)d_in[7];
    const float* bvr  = (const float*)d_in[8];
    float* out = (float*)d_out;
    const int B = in_sizes[0] / (CF * HW);

    hipLaunchKernelGGL(fused_kernel, dim3(KTOP / 4, B), dim3(1024), 0, stream,
                       attn, lf, pt, cw, cb, bg, bb, bm, bvr, out);
}